// Round 6
// baseline (32.705 us; speedup 1.0000x reference)
//
#include <hip/hip_runtime.h>
#include <math.h>

#define L_SEQ 4096   // sequence length L
#define NT 256       // threads per block (one block per sequence)
#define CHUNK 16     // elements per thread
#define NW (NT/64)   // waves per block (4)

struct M2 { float a00, a01, a10, a11; };

// max-plus 2x2 compose: C[s][t] = max_k(A[s][k] + B[k][t])
__device__ __forceinline__ M2 mpc(const M2& A, const M2& B) {
  M2 C;
  C.a00 = fmaxf(A.a00 + B.a00, A.a01 + B.a10);
  C.a01 = fmaxf(A.a00 + B.a01, A.a01 + B.a11);
  C.a10 = fmaxf(A.a10 + B.a00, A.a11 + B.a10);
  C.a11 = fmaxf(A.a10 + B.a01, A.a11 + B.a11);
  return C;
}

// row-vector max-plus apply: r[t] = max_s(m[s] + M[s][t])
__device__ __forceinline__ void mapply(float m0, float m1, const M2& M,
                                       float& r0, float& r1) {
  r0 = fmaxf(m0 + M.a00, m1 + M.a10);
  r1 = fmaxf(m0 + M.a01, m1 + M.a11);
}

__device__ __forceinline__ M2 ldm(const float4& v) { return M2{v.x, v.y, v.z, v.w}; }
__device__ __forceinline__ float4 stm(const M2& m) { return make_float4(m.a00, m.a01, m.a10, m.a11); }
__device__ __forceinline__ unsigned rev4(unsigned x) {
  return ((x & 1u) << 3) | ((x & 2u) << 1) | ((x & 4u) >> 1) | ((x & 8u) >> 3);
}

__global__ __launch_bounds__(NT, 8) void chain_fb_kernel(
    const float* __restrict__ jp, const float* __restrict__ bp,
    const int* __restrict__ obs, float* __restrict__ out) {
  __shared__ float4 T4s[16];                                // 4-bit transforms (AoS, build only)
  __shared__ float T4a[16], T4b[16], T4c[16], T4d[16];      // 4-bit LUT, SoA
  __shared__ float T8a[256], T8b[256], T8c[256], T8d[256];  // 8-bit LUT, SoA (4 KB)
  __shared__ float4 wtf[NW];   // forward wave totals
  __shared__ float4 wtb[NW];   // backward wave totals

  const int t = threadIdx.x;
  const int lane = t & 63;
  const int w = t >> 6;
  const long b = blockIdx.x;

  const float P   = 0.25f * jp[0];   // psi = [[P,-P],[-P,P]]
  const float hb0 = 0.5f * bp[0];    // u_i = 0.5*b[obs_i]; phi_i = (-u, +u)
  const float hb1 = 0.5f * bp[1];

  // ---- issue obs loads first (latency hidden under LUT build)
  const int4* rowp = (const int4*)(obs + b * L_SEQ + (long)t * CHUNK);
  int4 q0 = rowp[0], q1 = rowp[1], q2 = rowp[2], q3 = rowp[3];

  // ---- build T4 LUT: pattern p -> E(p0)(*)E(p1)(*)E(p2)(*)E(p3), bit0 earliest
  //      E(u) = [[P-u, -u-P],[u-P, u+P]]
  if (t < 16) {
    float u0 = (t & 1) ? hb1 : hb0;
    M2 Tt{P - u0, -u0 - P, u0 - P, u0 + P};
    #pragma unroll
    for (int k = 1; k < 4; ++k) {
      float uk = ((t >> k) & 1) ? hb1 : hb0;
      M2 Ek{P - uk, -uk - P, uk - P, uk + P};
      Tt = mpc(Tt, Ek);
    }
    T4s[t] = stm(Tt);
    T4a[t] = Tt.a00; T4b[t] = Tt.a01; T4c[t] = Tt.a10; T4d[t] = Tt.a11;
  }
  __syncthreads();
  {  // T8[p] = T4[p&15] (*) T4[p>>4]  — one entry per thread (NT==256)
    M2 M = mpc(ldm(T4s[t & 15]), ldm(T4s[(t >> 4) & 15]));
    T8a[t] = M.a00; T8b[t] = M.a01; T8c[t] = M.a10; T8d[t] = M.a11;
  }
  // pack 16-bit obs mask while the barrier drains
  const unsigned m =
      (unsigned)(q0.x & 1)        | (unsigned)(q0.y & 1) << 1  |
      (unsigned)(q0.z & 1) << 2   | (unsigned)(q0.w & 1) << 3  |
      (unsigned)(q1.x & 1) << 4   | (unsigned)(q1.y & 1) << 5  |
      (unsigned)(q1.z & 1) << 6   | (unsigned)(q1.w & 1) << 7  |
      (unsigned)(q2.x & 1) << 8   | (unsigned)(q2.y & 1) << 9  |
      (unsigned)(q2.z & 1) << 10  | (unsigned)(q2.w & 1) << 11 |
      (unsigned)(q3.x & 1) << 12  | (unsigned)(q3.y & 1) << 13 |
      (unsigned)(q3.z & 1) << 14  | (unsigned)(q3.w & 1) << 15;
  __syncthreads();

  // ---- chunk transforms: 2 SoA lookups + 1 compose per direction
  const unsigned r16 = __brev(m) >> 16;    // 16-bit reversal: bwd element order
  const unsigned mlo = m & 255, mhi = (m >> 8) & 255;
  const unsigned rlo = r16 & 255, rhi = (r16 >> 8) & 255;
  M2 T = mpc(M2{T8a[mlo], T8b[mlo], T8c[mlo], T8d[mlo]},
             M2{T8a[mhi], T8b[mhi], T8c[mhi], T8d[mhi]});   // fwd: E(u0)..E(u15)
  M2 R = mpc(M2{T8a[rlo], T8b[rlo], T8c[rlo], T8d[rlo]},
             M2{T8a[rhi], T8b[rhi], T8c[rhi], T8d[rhi]});   // bwd: E(u15)..E(u0)

  // ---- fused Hillis-Steele scans: prefix (shfl_up) + suffix (shfl_down)
  #pragma unroll
  for (int off = 1; off < 64; off <<= 1) {
    M2 OF{__shfl_up(T.a00, off), __shfl_up(T.a01, off),
          __shfl_up(T.a10, off), __shfl_up(T.a11, off)};
    M2 OB{__shfl_down(R.a00, off), __shfl_down(R.a01, off),
          __shfl_down(R.a10, off), __shfl_down(R.a11, off)};
    if (lane >= off)      T = mpc(OF, T);   // earlier-in-order on the left
    if (lane < 64 - off)  R = mpc(OB, R);   // higher-index on the left
  }
  if (lane == 63) wtf[w] = stm(T);
  if (lane == 0)  wtb[w] = stm(R);

  // intra-wave exclusive versions
  M2 EF{__shfl_up(T.a00, 1), __shfl_up(T.a01, 1),
        __shfl_up(T.a10, 1), __shfl_up(T.a11, 1)};
  M2 EB{__shfl_down(R.a00, 1), __shfl_down(R.a01, 1),
        __shfl_down(R.a10, 1), __shfl_down(R.a11, 1)};
  if (lane == 0)  { EF.a00 = 0.f; EF.a01 = -INFINITY; EF.a10 = -INFINITY; EF.a11 = 0.f; }
  if (lane == 63) { EB.a00 = 0.f; EB.a01 = -INFINITY; EB.a10 = -INFINITY; EB.a11 = 0.f; }

  __syncthreads();  // wave totals visible

  M2 GF = EF, GB = EB;
  for (int ww = w - 1; ww >= 0; --ww) GF = mpc(ldm(wtf[ww]), GF);
  for (int ww = w + 1; ww < NW; ++ww) GB = mpc(ldm(wtb[ww]), GB);
  // apply zero init vector: msg[t] = max_s G[s][t]
  const float fm0 = fmaxf(GF.a00, GF.a10), fm1 = fmaxf(GF.a01, GF.a11);
  const float bm0 = fmaxf(GB.a00, GB.a10), bm1 = fmaxf(GB.a01, GB.a11);

  // ---- jumped replay: T4 lookups bring messages to 4-elem group boundaries,
  //      then 4 independent short walks per direction (ILP instead of one
  //      16-step serial chain).
  const unsigned p0 = m & 15, p1 = (m >> 4) & 15, p2 = (m >> 8) & 15, p3 = (m >> 12) & 15;

  // fwd boundary msgs: Fg = msg incoming at element 4g
  float F0x = fm0, F0y = fm1, F1x, F1y, F2x, F2y, F3x, F3y;
  mapply(F0x, F0y, M2{T4a[p0], T4b[p0], T4c[p0], T4d[p0]}, F1x, F1y);
  mapply(F1x, F1y, M2{T4a[p1], T4b[p1], T4c[p1], T4d[p1]}, F2x, F2y);
  mapply(F2x, F2y, M2{T4a[p2], T4b[p2], T4c[p2], T4d[p2]}, F3x, F3y);

  // bwd boundary msgs: Bg = msg incoming at element 4g+3 (from elements beyond)
  const unsigned rp3 = rev4(p3), rp2 = rev4(p2), rp1 = rev4(p1);
  float B3x = bm0, B3y = bm1, B2x, B2y, B1x, B1y, B0x, B0y;
  mapply(B3x, B3y, M2{T4a[rp3], T4b[rp3], T4c[rp3], T4d[rp3]}, B2x, B2y);
  mapply(B2x, B2y, M2{T4a[rp2], T4b[rp2], T4c[rp2], T4d[rp2]}, B1x, B1y);
  mapply(B1x, B1y, M2{T4a[rp1], T4b[rp1], T4c[rp1], T4d[rp1]}, B0x, B0y);

  float* r0 = out + b * (2L * L_SEQ) + (long)t * CHUNK;   // out[b][0][t*16..]
  float* r1 = r0 + L_SEQ;                                  // out[b][1][...]

  #pragma unroll
  for (int g = 0; g < 4; ++g) {
    const float Fx = (g == 0) ? F0x : (g == 1) ? F1x : (g == 2) ? F2x : F3x;
    const float Fy = (g == 0) ? F0y : (g == 1) ? F1y : (g == 2) ? F2y : F3y;
    const float Bx = (g == 0) ? B0x : (g == 1) ? B1x : (g == 2) ? B2x : B3x;
    const float By = (g == 0) ? B0y : (g == 1) ? B1y : (g == 2) ? B2y : B3y;

    // bwd walk within group: be[k] = bwd msg incoming at element 4g+k
    float be0[4], be1[4];
    be0[3] = Bx; be1[3] = By;
    #pragma unroll
    for (int k = 2; k >= 0; --k) {
      const float u = ((m >> (4 * g + k + 1)) & 1) ? hb1 : hb0;
      const float x = be0[k + 1] - u, y = be1[k + 1] + u;
      be0[k] = fmaxf(x + P, y - P);
      be1[k] = fmaxf(x - P, y + P);
    }
    // fwd walk + fused output: o = (phi + fwd) + bwd
    float o0[4], o1[4];
    float mfx = Fx, mfy = Fy;
    #pragma unroll
    for (int k = 0; k < 4; ++k) {
      const float u = ((m >> (4 * g + k)) & 1) ? hb1 : hb0;
      const float x = mfx - u, y = mfy + u;
      o0[k] = x + be0[k];
      o1[k] = y + be1[k];
      mfx = fmaxf(x + P, y - P);
      mfy = fmaxf(x - P, y + P);
    }
    ((float4*)(r0 + 4 * g))[0] = make_float4(o0[0], o0[1], o0[2], o0[3]);
    ((float4*)(r1 + 4 * g))[0] = make_float4(o1[0], o1[1], o1[2], o1[3]);
  }
}

extern "C" void kernel_launch(void* const* d_in, const int* in_sizes, int n_in,
                              void* d_out, int out_size, void* d_ws, size_t ws_size,
                              hipStream_t stream) {
  const float* jp  = (const float*)d_in[0];
  const float* bp  = (const float*)d_in[1];
  const int*   obs = (const int*)d_in[2];
  float* out = (float*)d_out;
  const int B = in_sizes[2] / L_SEQ;   // 2048
  chain_fb_kernel<<<B, NT, 0, stream>>>(jp, bp, obs, out);
}

// Round 7
// 31.777 us; speedup vs baseline: 1.0292x; 1.0292x over previous
//
#include <hip/hip_runtime.h>
#include <math.h>

#define L_SEQ 4096      // sequence length L
#define NT 256          // threads per block
#define CHUNK 8         // elements per thread
#define NW (NT/64)      // waves per block (4)
#define HALF (NT*CHUNK) // elements per half-block (2048)

struct M2 { float a00, a01, a10, a11; };

// max-plus 2x2 compose: C[s][t] = max_k(A[s][k] + B[k][t])
__device__ __forceinline__ M2 mpc(const M2& A, const M2& B) {
  M2 C;
  C.a00 = fmaxf(A.a00 + B.a00, A.a01 + B.a10);
  C.a01 = fmaxf(A.a00 + B.a01, A.a01 + B.a11);
  C.a10 = fmaxf(A.a10 + B.a00, A.a11 + B.a10);
  C.a11 = fmaxf(A.a10 + B.a01, A.a11 + B.a11);
  return C;
}

// row-vector max-plus apply: r[t] = max_s(m[s] + M[s][t])
__device__ __forceinline__ void mapply(float m0, float m1, const M2& M,
                                       float& r0, float& r1) {
  r0 = fmaxf(m0 + M.a00, m1 + M.a10);
  r1 = fmaxf(m0 + M.a01, m1 + M.a11);
}

__device__ __forceinline__ M2 ldm(const float4& v) { return M2{v.x, v.y, v.z, v.w}; }
__device__ __forceinline__ float4 stm(const M2& m) { return make_float4(m.a00, m.a01, m.a10, m.a11); }

__global__ __launch_bounds__(NT, 8) void chain_fb_kernel(
    const float* __restrict__ jp, const float* __restrict__ bp,
    const int* __restrict__ obs, float* __restrict__ out,
    float* __restrict__ ws) {
  __shared__ float4 T4s[16];                                // 4-bit-pattern transforms
  __shared__ float T8a[256], T8b[256], T8c[256], T8d[256];  // 8-bit LUT, SoA (4 KB)
  __shared__ float4 wtf[NW];   // forward wave totals
  __shared__ float4 wtb[NW];   // backward wave totals
  __shared__ float vin_s[2];   // partner's boundary message

  const int t = threadIdx.x;
  const int lane = t & 63;
  const int w = t >> 6;
  const int blk = blockIdx.x;
  const int half = blk & 1;        // 0 = left half of seq, 1 = right half
  const long seq = blk >> 1;
  const int partner = blk ^ 1;     // adjacent pair -> co-resident, deadlock-free

  const float P   = 0.25f * jp[0];   // psi = [[P,-P],[-P,P]]
  const float hb0 = 0.5f * bp[0];    // u_i = 0.5*b[obs_i]; phi_i = (-u, +u)
  const float hb1 = 0.5f * bp[1];

  // ---- issue obs loads first (latency hidden under LUT build)
  const int4* rowp = (const int4*)(obs + seq * L_SEQ + half * HALF + (long)t * CHUNK);
  int4 q0 = rowp[0], q1 = rowp[1];

  // ---- build LUT: pattern p -> E(p0)(*)E(p1)(*)... (bit 0 = earliest elem)
  //      E(u) = [[P-u, -u-P],[u-P, u+P]]
  if (t < 16) {
    float u0 = (t & 1) ? hb1 : hb0;
    M2 Tt{P - u0, -u0 - P, u0 - P, u0 + P};
    #pragma unroll
    for (int k = 1; k < 4; ++k) {
      float uk = ((t >> k) & 1) ? hb1 : hb0;
      M2 Ek{P - uk, -uk - P, uk - P, uk + P};
      Tt = mpc(Tt, Ek);
    }
    T4s[t] = stm(Tt);
  }
  __syncthreads();
  {  // T8[p] = T4[p&15] (*) T4[p>>4] — one entry per thread (NT==256)
    M2 M = mpc(ldm(T4s[t & 15]), ldm(T4s[(t >> 4) & 15]));
    T8a[t] = M.a00; T8b[t] = M.a01; T8c[t] = M.a10; T8d[t] = M.a11;
  }
  // pack obs bit mask while the barrier drains
  const unsigned m =
      (unsigned)(q0.x & 1)       | (unsigned)(q0.y & 1) << 1 |
      (unsigned)(q0.z & 1) << 2  | (unsigned)(q0.w & 1) << 3 |
      (unsigned)(q1.x & 1) << 4  | (unsigned)(q1.y & 1) << 5 |
      (unsigned)(q1.z & 1) << 6  | (unsigned)(q1.w & 1) << 7;
  __syncthreads();

  // ---- chunk transforms: pure lookups (bwd = bit-reversed pattern)
  const unsigned r = __brev(m) >> 24;
  M2 T{T8a[m], T8b[m], T8c[m], T8d[m]};   // fwd: E(u0)(*)...(*)E(u7)
  M2 R{T8a[r], T8b[r], T8c[r], T8d[r]};   // bwd: E(u7)(*)...(*)E(u0)

  // ---- fused Hillis-Steele scans: prefix (shfl_up) + suffix (shfl_down)
  #pragma unroll
  for (int off = 1; off < 64; off <<= 1) {
    M2 OF{__shfl_up(T.a00, off), __shfl_up(T.a01, off),
          __shfl_up(T.a10, off), __shfl_up(T.a11, off)};
    M2 OB{__shfl_down(R.a00, off), __shfl_down(R.a01, off),
          __shfl_down(R.a10, off), __shfl_down(R.a11, off)};
    if (lane >= off)      T = mpc(OF, T);   // earlier-in-order on the left
    if (lane < 64 - off)  R = mpc(OB, R);   // higher-index on the left
  }
  if (lane == 63) wtf[w] = stm(T);
  if (lane == 0)  wtb[w] = stm(R);

  // intra-wave exclusive versions
  M2 EF{__shfl_up(T.a00, 1), __shfl_up(T.a01, 1),
        __shfl_up(T.a10, 1), __shfl_up(T.a11, 1)};
  M2 EB{__shfl_down(R.a00, 1), __shfl_down(R.a01, 1),
        __shfl_down(R.a10, 1), __shfl_down(R.a11, 1)};
  if (lane == 0)  { EF.a00 = 0.f; EF.a01 = -INFINITY; EF.a10 = -INFINITY; EF.a11 = 0.f; }
  if (lane == 63) { EB.a00 = 0.f; EB.a01 = -INFINITY; EB.a10 = -INFINITY; EB.a11 = 0.f; }

  __syncthreads();  // wave totals visible

  // ---- boundary exchange with partner half-block (publish THEN spin; all
  //      traffic through device-scope atomics; sentinel 0xFFFFFFFF = NaN)
  if (t == 0) {
    M2 tot;
    if (half == 0)   // left half publishes colmax of its fwd total
      tot = mpc(mpc(ldm(wtf[0]), ldm(wtf[1])), mpc(ldm(wtf[2]), ldm(wtf[3])));
    else             // right half publishes colmax of its bwd total
      tot = mpc(mpc(ldm(wtb[3]), ldm(wtb[2])), mpc(ldm(wtb[1]), ldm(wtb[0])));
    atomicExch(&ws[2 * blk + 0], fmaxf(tot.a00, tot.a10));
    atomicExch(&ws[2 * blk + 1], fmaxf(tot.a01, tot.a11));
    float p0, p1;
    do { p0 = atomicAdd(&ws[2 * partner + 0], 0.0f); }
    while (__float_as_uint(p0) == 0xFFFFFFFFu);
    do { p1 = atomicAdd(&ws[2 * partner + 1], 0.0f); }
    while (__float_as_uint(p1) == 0xFFFFFFFFu);
    vin_s[0] = p0; vin_s[1] = p1;
  }

  // cross-wave exclusive composition (independent of the exchange)
  M2 GF = EF, GB = EB;
  for (int ww = w - 1; ww >= 0; --ww) GF = mpc(ldm(wtf[ww]), GF);
  for (int ww = w + 1; ww < NW; ++ww) GB = mpc(ldm(wtb[ww]), GB);

  __syncthreads();  // vin_s visible

  // incoming messages at this thread's chunk boundaries
  float fm0, fm1, bm0, bm1;
  if (half == 0) {
    fm0 = fmaxf(GF.a00, GF.a10); fm1 = fmaxf(GF.a01, GF.a11);  // seq start: zero init
    mapply(vin_s[0], vin_s[1], GB, bm0, bm1);                  // bwd comes from right half
  } else {
    mapply(vin_s[0], vin_s[1], GF, fm0, fm1);                  // fwd comes from left half
    bm0 = fmaxf(GB.a00, GB.a10); bm1 = fmaxf(GB.a01, GB.a11);  // seq end: zero init
  }

  // ---- fwd replay: o = phi + fwd  (x,y are exactly phi+msg)
  float o0[CHUNK], o1[CHUNK];
  #pragma unroll
  for (int e = 0; e < CHUNK; ++e) {
    float u = ((m >> e) & 1) ? hb1 : hb0;
    float x = fm0 - u, y = fm1 + u;
    o0[e] = x; o1[e] = y;
    fm0 = fmaxf(x + P, y - P);
    fm1 = fmaxf(x - P, y + P);
  }
  // ---- bwd replay: add bwd message (right->left)
  #pragma unroll
  for (int e = CHUNK - 1; e >= 0; --e) {
    float u = ((m >> e) & 1) ? hb1 : hb0;
    o0[e] += bm0; o1[e] += bm1;
    float x = bm0 - u, y = bm1 + u;
    bm0 = fmaxf(x + P, y - P);
    bm1 = fmaxf(x - P, y + P);
  }

  // ---- store: contiguous 8 floats per state row (coalesced float4s)
  const long base = (long)t * CHUNK + half * HALF;
  float* r0 = out + seq * (2L * L_SEQ) + base;   // out[seq][0][base..]
  float* r1 = r0 + L_SEQ;                        // out[seq][1][base..]
  ((float4*)r0)[0] = make_float4(o0[0], o0[1], o0[2], o0[3]);
  ((float4*)r0)[1] = make_float4(o0[4], o0[5], o0[6], o0[7]);
  ((float4*)r1)[0] = make_float4(o1[0], o1[1], o1[2], o1[3]);
  ((float4*)r1)[1] = make_float4(o1[4], o1[5], o1[6], o1[7]);
}

extern "C" void kernel_launch(void* const* d_in, const int* in_sizes, int n_in,
                              void* d_out, int out_size, void* d_ws, size_t ws_size,
                              hipStream_t stream) {
  const float* jp  = (const float*)d_in[0];
  const float* bp  = (const float*)d_in[1];
  const int*   obs = (const int*)d_in[2];
  float* out = (float*)d_out;
  float* ws  = (float*)d_ws;
  const int B  = in_sizes[2] / L_SEQ;   // 2048
  const int nb = 2 * B;                 // 4096 half-blocks, pairs (2b, 2b+1)
  // sentinel-fill the exchange buffer (0xFFFFFFFF = NaN), then launch
  hipMemsetAsync(ws, 0xFF, (size_t)nb * 2 * sizeof(float), stream);
  chain_fb_kernel<<<nb, NT, 0, stream>>>(jp, bp, obs, out, ws);
}

// Round 8
// 24.605 us; speedup vs baseline: 1.3292x; 1.2915x over previous
//
#include <hip/hip_runtime.h>
#include <math.h>

#define L_SEQ 4096   // sequence length L
#define NT 512       // threads per block (one block per sequence)
#define CHUNK 8      // elements per thread
#define NW (NT/64)   // waves per block (8)

struct M2 { float a00, a01, a10, a11; };

// max-plus 2x2 compose: C[s][t] = max_k(A[s][k] + B[k][t])
__device__ __forceinline__ M2 mpc(const M2& A, const M2& B) {
  M2 C;
  C.a00 = fmaxf(A.a00 + B.a00, A.a01 + B.a10);
  C.a01 = fmaxf(A.a00 + B.a01, A.a01 + B.a11);
  C.a10 = fmaxf(A.a10 + B.a00, A.a11 + B.a10);
  C.a11 = fmaxf(A.a10 + B.a01, A.a11 + B.a11);
  return C;
}

__device__ __forceinline__ M2 ldm(const float4& v) { return M2{v.x, v.y, v.z, v.w}; }
__device__ __forceinline__ float4 stm(const M2& m) { return make_float4(m.a00, m.a01, m.a10, m.a11); }

// DPP cross-lane fetch (VALU pipe, no LDS traffic). ctrl: 0x110+N = row_shr:N,
// 0x142 = row_bcast:15 (lane15->lanes16-31, lane31->32-47, lane47->48-63),
// 0x143 = row_bcast:31 (lane31 -> lanes 32-63).
template <int CTRL>
__device__ __forceinline__ float dppf(float x) {
  return __int_as_float(__builtin_amdgcn_update_dpp(
      0, __float_as_int(x), CTRL, 0xf, 0xf, true));
}
template <int CTRL>
__device__ __forceinline__ M2 dpp_fetch(const M2& x) {
  M2 r;
  r.a00 = dppf<CTRL>(x.a00); r.a01 = dppf<CTRL>(x.a01);
  r.a10 = dppf<CTRL>(x.a10); r.a11 = dppf<CTRL>(x.a11);
  return r;
}

__global__ __launch_bounds__(NT, 8) void chain_fb_kernel(
    const float* __restrict__ jp, const float* __restrict__ bp,
    const int* __restrict__ obs, float* __restrict__ out) {
  __shared__ float4 T4s[16];                                // 4-bit-pattern transforms
  __shared__ float T8a[256], T8b[256], T8c[256], T8d[256];  // 8-bit LUT, SoA (4 KB)
  __shared__ float4 wtf[NW];   // forward wave totals
  __shared__ float4 wtb[NW];   // backward wave totals

  const int t = threadIdx.x;
  const int lane = t & 63;
  const int w = t >> 6;
  const long b = blockIdx.x;

  const float P   = 0.25f * jp[0];   // psi = [[P,-P],[-P,P]]
  const float hb0 = 0.5f * bp[0];    // u_i = 0.5*b[obs_i]; phi_i = (-u, +u)
  const float hb1 = 0.5f * bp[1];

  // ---- issue obs loads first (latency hidden under LUT build)
  const int4* rowp = (const int4*)(obs + b * L_SEQ + (long)t * CHUNK);
  int4 q0 = rowp[0], q1 = rowp[1];

  // ---- build LUT: pattern p -> E(p0)(*)E(p1)(*)... (bit 0 = earliest elem)
  //      E(u) = [[P-u, -u-P],[u-P, u+P]]
  if (t < 16) {
    float u0 = (t & 1) ? hb1 : hb0;
    M2 Tt{P - u0, -u0 - P, u0 - P, u0 + P};
    #pragma unroll
    for (int k = 1; k < 4; ++k) {
      float uk = ((t >> k) & 1) ? hb1 : hb0;
      M2 Ek{P - uk, -uk - P, uk - P, uk + P};
      Tt = mpc(Tt, Ek);
    }
    T4s[t] = stm(Tt);
  }
  __syncthreads();
  if (t < 256) {  // T8[p] = T4[p&15] (*) T4[p>>4]
    M2 M = mpc(ldm(T4s[t & 15]), ldm(T4s[(t >> 4) & 15]));
    T8a[t] = M.a00; T8b[t] = M.a01; T8c[t] = M.a10; T8d[t] = M.a11;
  }
  // pack obs bit mask while the barrier drains
  const unsigned m =
      (unsigned)(q0.x & 1)       | (unsigned)(q0.y & 1) << 1 |
      (unsigned)(q0.z & 1) << 2  | (unsigned)(q0.w & 1) << 3 |
      (unsigned)(q1.x & 1) << 4  | (unsigned)(q1.y & 1) << 5 |
      (unsigned)(q1.z & 1) << 6  | (unsigned)(q1.w & 1) << 7;
  __syncthreads();

  // ---- chunk transforms.
  // Fwd: this thread's chunk. Bwd (v-space): v-lane l handles chunk 63-l of
  // this wave, so the suffix scan becomes a SECOND forward scan.
  const unsigned mrev = (unsigned)__shfl((int)m, 63 - lane);   // mirrored chunk's mask
  const unsigned r = __brev(mrev) >> 24;                       // its bwd-order pattern
  M2 T {T8a[m], T8b[m], T8c[m], T8d[m]};   // fwd: E(u0)(*)...(*)E(u7)
  M2 Rv{T8a[r], T8b[r], T8c[r], T8d[r]};   // bwd of chunk 63-lane

  // ---- dual Hillis-Steele inclusive scans, cross-lane via DPP (VALU pipe)
  {
    M2 f, g;
    f = dpp_fetch<0x111>(T); g = dpp_fetch<0x111>(Rv);           // row_shr:1
    if ((lane & 15) >= 1) { T = mpc(f, T); Rv = mpc(g, Rv); }
    f = dpp_fetch<0x112>(T); g = dpp_fetch<0x112>(Rv);           // row_shr:2
    if ((lane & 15) >= 2) { T = mpc(f, T); Rv = mpc(g, Rv); }
    f = dpp_fetch<0x114>(T); g = dpp_fetch<0x114>(Rv);           // row_shr:4
    if ((lane & 15) >= 4) { T = mpc(f, T); Rv = mpc(g, Rv); }
    f = dpp_fetch<0x118>(T); g = dpp_fetch<0x118>(Rv);           // row_shr:8
    if ((lane & 15) >= 8) { T = mpc(f, T); Rv = mpc(g, Rv); }
    f = dpp_fetch<0x142>(T); g = dpp_fetch<0x142>(Rv);           // row_bcast:15
    if (lane & 16)        { T = mpc(f, T); Rv = mpc(g, Rv); }    // rows 1,3
    f = dpp_fetch<0x143>(T); g = dpp_fetch<0x143>(Rv);           // row_bcast:31
    if (lane >= 32)       { T = mpc(f, T); Rv = mpc(g, Rv); }    // rows 2,3
  }
  if (lane == 63) { wtf[w] = stm(T); wtb[w] = stm(Rv); }  // full wave totals

  // intra-wave exclusive versions (shift by 1; identity at lane 0)
  M2 EF{__shfl_up(T.a00, 1), __shfl_up(T.a01, 1),
        __shfl_up(T.a10, 1), __shfl_up(T.a11, 1)};
  M2 EB{__shfl_up(Rv.a00, 1), __shfl_up(Rv.a01, 1),
        __shfl_up(Rv.a10, 1), __shfl_up(Rv.a11, 1)};
  if (lane == 0) {
    EF.a00 = 0.f; EF.a01 = -INFINITY; EF.a10 = -INFINITY; EF.a11 = 0.f;
    EB.a00 = 0.f; EB.a01 = -INFINITY; EB.a10 = -INFINITY; EB.a11 = 0.f;
  }

  __syncthreads();  // wave totals visible

  // cross-wave exclusive composition (earlier waves left for fwd; later waves
  // left for bwd — wtb[ww] is already the wave's total in bwd order)
  M2 GF = EF, GB = EB;
  for (int ww = w - 1; ww >= 0; --ww) GF = mpc(ldm(wtf[ww]), GF);
  for (int ww = w + 1; ww < NW; ++ww) GB = mpc(ldm(wtb[ww]), GB);
  // apply zero init vector: msg[t] = max_s G[s][t]
  float fm0 = fmaxf(GF.a00, GF.a10), fm1 = fmaxf(GF.a01, GF.a11);
  const float bv0 = fmaxf(GB.a00, GB.a10), bv1 = fmaxf(GB.a01, GB.a11);
  // bwd message computed at v-lane (63-lane): swap back (2 bpermutes)
  float bm0 = __shfl(bv0, 63 - lane);
  float bm1 = __shfl(bv1, 63 - lane);

  // ---- fwd replay: o = phi + fwd  (x,y are exactly phi+msg)
  float o0[CHUNK], o1[CHUNK];
  #pragma unroll
  for (int e = 0; e < CHUNK; ++e) {
    float u = ((m >> e) & 1) ? hb1 : hb0;
    float x = fm0 - u, y = fm1 + u;
    o0[e] = x; o1[e] = y;
    fm0 = fmaxf(x + P, y - P);
    fm1 = fmaxf(x - P, y + P);
  }
  // ---- bwd replay: add bwd message (right->left)
  #pragma unroll
  for (int e = CHUNK - 1; e >= 0; --e) {
    float u = ((m >> e) & 1) ? hb1 : hb0;
    o0[e] += bm0; o1[e] += bm1;
    float x = bm0 - u, y = bm1 + u;
    bm0 = fmaxf(x + P, y - P);
    bm1 = fmaxf(x - P, y + P);
  }

  // ---- store: contiguous 8 floats per state row (coalesced float4s)
  const long base = (long)t * CHUNK;
  float* r0 = out + b * (2L * L_SEQ) + base;   // out[b][0][base..]
  float* r1 = r0 + L_SEQ;                      // out[b][1][base..]
  ((float4*)r0)[0] = make_float4(o0[0], o0[1], o0[2], o0[3]);
  ((float4*)r0)[1] = make_float4(o0[4], o0[5], o0[6], o0[7]);
  ((float4*)r1)[0] = make_float4(o1[0], o1[1], o1[2], o1[3]);
  ((float4*)r1)[1] = make_float4(o1[4], o1[5], o1[6], o1[7]);
}

extern "C" void kernel_launch(void* const* d_in, const int* in_sizes, int n_in,
                              void* d_out, int out_size, void* d_ws, size_t ws_size,
                              hipStream_t stream) {
  const float* jp  = (const float*)d_in[0];
  const float* bp  = (const float*)d_in[1];
  const int*   obs = (const int*)d_in[2];
  float* out = (float*)d_out;
  const int B = in_sizes[2] / L_SEQ;   // 2048
  chain_fb_kernel<<<B, NT, 0, stream>>>(jp, bp, obs, out);
}